// Round 2
// baseline (219.296 us; speedup 1.0000x reference)
//
#include <hip/hip_runtime.h>

// GridSamplePScan: out[b,t,c] = sum_{k<=t} bilinear(images[b,k,c], base_grid + (cum[t]-cum[k]))
// B=2, L=24, C=16, H=W=64, fp32. align_corners=False, zero padding, x wrapped into [-1,1).
//
// Correctness-critical: the x-wrap is the only discontinuity. rel = cum[t]-cum[k] is
// computed with the EXACT sequential ascending add order of jnp.cumsum (two-pass),
// so wrap decisions match the reference bit-for-bit. The wrap itself uses an exact
// fmod-by-2 (v - 2*trunc(v*0.5), exact for |v|<4) + the same negative-adjust rounding.

#define BB 2
#define LL 24
#define CC 16
#define HH 64
#define WW 64
#define HW (HH * WW)

__global__ __launch_bounds__(64) void gsps_kernel(
    const float* __restrict__ flows,   // [B,L,2,H,W]
    const float* __restrict__ images,  // [B,L,C,H,W]
    float* __restrict__ out)           // [B,L,C,H,W]
{
    const int bid = blockIdx.x;
    const int t = (LL - 1) - (bid % LL);   // big-t blocks first: better makespan tail
    const int y = (bid / LL) % HH;
    const int b = bid / (LL * HH);
    const int x = threadIdx.x;             // one wave = one image row

    // base grid: linspace(-1+1/64, 1-1/64, 64) -> exact multiples of 1/32, bit-exact
    const float gx = -0.984375f + (float)x * 0.03125f;
    const float gy = -0.984375f + (float)y * 0.03125f;

    const int pix = y * WW + x;
    const float* fb = flows + (size_t)b * LL * 2 * HW + pix;

    // ---- pass 1: cum[t] in ascending sequential order (matches jnp.cumsum) ----
    float ctx = 0.0f, cty = 0.0f;
    for (int i = 0; i <= t; ++i) {
        ctx += fb[(i * 2 + 0) * HW];
        cty += fb[(i * 2 + 1) * HW];
    }

    float acc[CC];
#pragma unroll
    for (int c = 0; c < CC; ++c) acc[c] = 0.0f;

    // ---- pass 2: running cum[k] (identical order => rel bit-matches reference) ----
    float cx = 0.0f, cy = 0.0f;
    for (int k = 0; k <= t; ++k) {
        cx += fb[(k * 2 + 0) * HW];
        cy += fb[(k * 2 + 1) * HW];
        const float relx = ctx - cx;       // cum[t] - cum[k]
        const float rely = cty - cy;

        // grid x, wrapped into [-1,1): remainder(gxv+1, 2) - 1
        const float gxv0 = gx + relx;
        const float v = gxv0 + 1.0f;
        float r = v - 2.0f * truncf(v * 0.5f);   // == fmodf(v, 2.0f), exact for |v|<4
        r = (r < 0.0f) ? (r + 2.0f) : r;         // Python remainder semantics
        const float gxv = r - 1.0f;
        const float gyv = gy + rely;

        const float ix = (gxv + 1.0f) * 32.0f - 0.5f;
        const float iy = (gyv + 1.0f) * 32.0f - 0.5f;

        const float x0f = floorf(ix);
        const float y0f = floorf(iy);
        const float x1f = x0f + 1.0f;
        const float y1f = y0f + 1.0f;

        const float wx1 = ix - x0f, wx0 = 1.0f - wx1;
        const float wy1 = iy - y0f, wy0 = 1.0f - wy1;

        const bool vx0 = (x0f >= 0.0f) && (x0f <= 63.0f);
        const bool vx1 = (x1f >= 0.0f) && (x1f <= 63.0f);
        const bool vy0 = (y0f >= 0.0f) && (y0f <= 63.0f);
        const bool vy1 = (y1f >= 0.0f) && (y1f <= 63.0f);

        const int x0 = min(max((int)x0f, 0), WW - 1);
        const int x1 = min(max((int)x1f, 0), WW - 1);
        const int y0 = min(max((int)y0f, 0), HH - 1);
        const int y1 = min(max((int)y1f, 0), HH - 1);

        const float w00 = (vx0 && vy0) ? (wx0 * wy0) : 0.0f;
        const float w10 = (vx1 && vy0) ? (wx1 * wy0) : 0.0f;
        const float w01 = (vx0 && vy1) ? (wx0 * wy1) : 0.0f;
        const float w11 = (vx1 && vy1) ? (wx1 * wy1) : 0.0f;

        const int i00 = y0 * WW + x0;
        const int i10 = y0 * WW + x1;
        const int i01 = y1 * WW + x0;
        const int i11 = y1 * WW + x1;

        const float* img = images + ((size_t)b * LL + k) * (CC * HW);
#pragma unroll
        for (int c = 0; c < CC; ++c) {
            const float* p = img + c * HW;   // uniform base (SGPR) + per-lane dword offset
            acc[c] += p[i00] * w00 + p[i10] * w10 + p[i01] * w01 + p[i11] * w11;
        }
    }

    float* o = out + ((size_t)b * LL + t) * (CC * HW) + pix;
#pragma unroll
    for (int c = 0; c < CC; ++c) o[c * HW] = acc[c];
}

extern "C" void kernel_launch(void* const* d_in, const int* in_sizes, int n_in,
                              void* d_out, int out_size, void* d_ws, size_t ws_size,
                              hipStream_t stream) {
    const float* flows  = (const float*)d_in[0];   // [B,L,2,H,W]
    const float* images = (const float*)d_in[1];   // [B,L,C,H,W]
    float* out = (float*)d_out;                    // [B,L,C,H,W]

    const int nblocks = BB * LL * HH;  // 3072 blocks x 64 threads (1 wave each)
    gsps_kernel<<<nblocks, 64, 0, stream>>>(flows, images, out);
}

// Round 4
// 169.532 us; speedup vs baseline: 1.2935x; 1.2935x over previous
//
#include <hip/hip_runtime.h>

// GridSamplePScan: out[b,t,c] = sum_{k<=t} bilinear(images[b,k,c], base_grid + (cum[t]-cum[k]))
// B=2, L=24, C=16, H=W=64 fp32. align_corners=False, zero pad, x wrapped into [-1,1).
//
// Structure: pre-transpose images to channels-last [B,L,H,W,C] in d_ws, then 256-thread
// blocks (4 waves x 4 channels each). Each corner gather = one dwordx4 (4 channels).
// Flow chain: two-pass ascending (bit-matches jnp.cumsum order). flow[k+1] prefetched
// before the gathers so consuming it never drains the gather vmcnt queue.
//
// R3 bug fixed here: wave channel byte-offset is cw*4 (cw in floats), NOT cw*16.

#define BB 2
#define LL 24
#define CC 16
#define HH 64
#define WW 64
#define HW (HH * WW)

// ---------- coordinate helper (exact wrap semantics) ----------
__device__ __forceinline__ void bilin_coords(
    float gxv0, float gyv,
    int& i00, int& i10, int& i01, int& i11,
    float& w00, float& w10, float& w01, float& w11)
{
    // wrap x into [-1,1): remainder(gxv0+1, 2) - 1; exact fmod for |v|<4
    const float v = gxv0 + 1.0f;
    float r = v - 2.0f * truncf(v * 0.5f);
    r = (r < 0.0f) ? (r + 2.0f) : r;
    const float gxv = r - 1.0f;

    const float ix = (gxv + 1.0f) * 32.0f - 0.5f;
    const float iy = (gyv + 1.0f) * 32.0f - 0.5f;

    const float x0f = floorf(ix);
    const float y0f = floorf(iy);
    const float x1f = x0f + 1.0f;
    const float y1f = y0f + 1.0f;

    const float wx1 = ix - x0f, wx0 = 1.0f - wx1;
    const float wy1 = iy - y0f, wy0 = 1.0f - wy1;

    const bool vx0 = (x0f >= 0.0f) && (x0f <= 63.0f);
    const bool vx1 = (x1f >= 0.0f) && (x1f <= 63.0f);
    const bool vy0 = (y0f >= 0.0f) && (y0f <= 63.0f);
    const bool vy1 = (y1f >= 0.0f) && (y1f <= 63.0f);

    const int x0 = min(max((int)x0f, 0), WW - 1);
    const int x1 = min(max((int)x1f, 0), WW - 1);
    const int y0 = min(max((int)y0f, 0), HH - 1);
    const int y1 = min(max((int)y1f, 0), HH - 1);

    w00 = (vx0 && vy0) ? (wx0 * wy0) : 0.0f;
    w10 = (vx1 && vy0) ? (wx1 * wy0) : 0.0f;
    w01 = (vx0 && vy1) ? (wx0 * wy1) : 0.0f;
    w11 = (vx1 && vy1) ? (wx1 * wy1) : 0.0f;

    i00 = y0 * WW + x0;
    i10 = y0 * WW + x1;
    i01 = y1 * WW + x0;
    i11 = y1 * WW + x1;
}

// ---------- kernel 1: images [B,L,C,H,W] -> imgT [B,L,H,W,C] ----------
__global__ __launch_bounds__(64) void transpose_kernel(
    const float* __restrict__ img, float* __restrict__ imgT)
{
    const int bid = blockIdx.x;            // (b*L + l)*H + y, total B*L*H = 3072
    const int y = bid % HH;
    const int l = (bid / HH) % LL;
    const int b = bid / (HH * LL);
    const int x = threadIdx.x;

    const float* src = img + ((size_t)(b * LL + l) * CC) * HW + y * WW + x;
    float v[CC];
#pragma unroll
    for (int c = 0; c < CC; ++c) v[c] = src[(size_t)c * HW];

    float* dst = imgT + ((size_t)(b * LL + l) * HW + y * WW + x) * CC;
#pragma unroll
    for (int c = 0; c < CC; c += 4)
        *(float4*)(dst + c) = make_float4(v[c], v[c + 1], v[c + 2], v[c + 3]);
}

// ---------- kernel 2: main (channels-last gathers, dwordx4 per corner) ----------
__global__ __launch_bounds__(256) void gsps_main(
    const float* __restrict__ flows,   // [B,L,2,H,W]
    const float* __restrict__ imgT,    // [B,L,H,W,C]
    float* __restrict__ out)           // [B,L,C,H,W]
{
    const int bid = blockIdx.x;
    const int t = (LL - 1) - (bid % LL);      // big-t first: makespan tail
    const int y = (bid / LL) % HH;
    const int b = bid / (LL * HH);
    const int x = threadIdx.x & 63;
    const int wave = threadIdx.x >> 6;        // 0..3
    const int cw = wave * 4;                  // this wave's channel base (in floats)

    const float gx = -0.984375f + (float)x * 0.03125f;
    const float gy = -0.984375f + (float)y * 0.03125f;
    const int pix = y * WW + x;
    const float* fb = flows + (size_t)b * LL * 2 * HW + pix;

    // pass 1: cum[t] in ascending sequential order (loads independent, adds serial)
    float ctx = 0.0f, cty = 0.0f;
    for (int i = 0; i <= t; ++i) {
        ctx += fb[(size_t)(i * 2) * HW];
        cty += fb[(size_t)(i * 2 + 1) * HW];
    }

    float4 acc = make_float4(0.0f, 0.0f, 0.0f, 0.0f);
    float cx = 0.0f, cy = 0.0f;
    float fxk = fb[0];
    float fyk = fb[HW];

    // per-(b,k) plane base; wave's channel slice at byte offset cw*4 within each
    // 64-byte pixel record (FIXED: was cw*16 = one whole pixel per wave)
    const char* ibase = (const char*)(imgT + (size_t)b * LL * HW * CC) + cw * 4;

    for (int k = 0; k <= t; ++k) {
        cx += fxk; cy += fyk;                 // cum[k] now in regs

        // prefetch flow[k+1] FIRST: oldest vmcnt entry, never forces gather drain
        if (k < t) {
            fxk = fb[(size_t)((k + 1) * 2) * HW];
            fyk = fb[(size_t)((k + 1) * 2 + 1) * HW];
        }

        int i00, i10, i01, i11;
        float w00, w10, w01, w11;
        bilin_coords(gx + (ctx - cx), gy + (cty - cy), i00, i10, i01, i11, w00, w10, w01, w11);

        const char* p = ibase + (size_t)k * (HW * CC * 4);
        const float4 v00 = *(const float4*)(p + (size_t)i00 * 64);
        const float4 v10 = *(const float4*)(p + (size_t)i10 * 64);
        const float4 v01 = *(const float4*)(p + (size_t)i01 * 64);
        const float4 v11 = *(const float4*)(p + (size_t)i11 * 64);

        acc.x += v00.x * w00 + v10.x * w10 + v01.x * w01 + v11.x * w11;
        acc.y += v00.y * w00 + v10.y * w10 + v01.y * w01 + v11.y * w11;
        acc.z += v00.z * w00 + v10.z * w10 + v01.z * w01 + v11.z * w11;
        acc.w += v00.w * w00 + v10.w * w10 + v01.w * w01 + v11.w * w11;
    }

    float* o = out + ((size_t)(b * LL + t) * CC + cw) * HW + pix;
    o[0]      = acc.x;
    o[HW]     = acc.y;
    o[2 * HW] = acc.z;
    o[3 * HW] = acc.w;
}

// ---------- fallback (ws too small): channels-first scalar gathers, 4 ch/wave ----------
__global__ __launch_bounds__(256) void gsps_direct(
    const float* __restrict__ flows,
    const float* __restrict__ images,  // [B,L,C,H,W]
    float* __restrict__ out)
{
    const int bid = blockIdx.x;
    const int t = (LL - 1) - (bid % LL);
    const int y = (bid / LL) % HH;
    const int b = bid / (LL * HH);
    const int x = threadIdx.x & 63;
    const int wave = threadIdx.x >> 6;
    const int cw = wave * 4;

    const float gx = -0.984375f + (float)x * 0.03125f;
    const float gy = -0.984375f + (float)y * 0.03125f;
    const int pix = y * WW + x;
    const float* fb = flows + (size_t)b * LL * 2 * HW + pix;

    float ctx = 0.0f, cty = 0.0f;
    for (int i = 0; i <= t; ++i) {
        ctx += fb[(size_t)(i * 2) * HW];
        cty += fb[(size_t)(i * 2 + 1) * HW];
    }

    float acc[4] = {0.0f, 0.0f, 0.0f, 0.0f};
    float cx = 0.0f, cy = 0.0f;
    float fxk = fb[0];
    float fyk = fb[HW];

    for (int k = 0; k <= t; ++k) {
        cx += fxk; cy += fyk;
        if (k < t) {
            fxk = fb[(size_t)((k + 1) * 2) * HW];
            fyk = fb[(size_t)((k + 1) * 2 + 1) * HW];
        }

        int i00, i10, i01, i11;
        float w00, w10, w01, w11;
        bilin_coords(gx + (ctx - cx), gy + (cty - cy), i00, i10, i01, i11, w00, w10, w01, w11);

        const float* img = images + (((size_t)(b * LL + k) * CC) + cw) * HW;
#pragma unroll
        for (int c = 0; c < 4; ++c) {
            const float* pc = img + (size_t)c * HW;
            acc[c] += pc[i00] * w00 + pc[i10] * w10 + pc[i01] * w01 + pc[i11] * w11;
        }
    }

    float* o = out + ((size_t)(b * LL + t) * CC + cw) * HW + pix;
#pragma unroll
    for (int c = 0; c < 4; ++c) o[(size_t)c * HW] = acc[c];
}

extern "C" void kernel_launch(void* const* d_in, const int* in_sizes, int n_in,
                              void* d_out, int out_size, void* d_ws, size_t ws_size,
                              hipStream_t stream) {
    const float* flows  = (const float*)d_in[0];   // [B,L,2,H,W]
    const float* images = (const float*)d_in[1];   // [B,L,C,H,W]
    float* out = (float*)d_out;                    // [B,L,C,H,W]

    const size_t needT = (size_t)BB * LL * CC * HW * sizeof(float);  // 12.6 MB
    const int nblk = BB * LL * HH;                                   // 3072

    if (ws_size >= needT) {
        float* imgT = (float*)d_ws;
        transpose_kernel<<<nblk, 64, 0, stream>>>(images, imgT);
        gsps_main<<<nblk, 256, 0, stream>>>(flows, imgT, out);
    } else {
        gsps_direct<<<nblk, 256, 0, stream>>>(flows, images, out);
    }
}

// Round 6
// 166.943 us; speedup vs baseline: 1.3136x; 1.0155x over previous
//
#include <hip/hip_runtime.h>

// GridSamplePScan: out[b,t,c] = sum_{k<=t} bilinear(images[b,k,c], base_grid + (cum[t]-cum[k]))
// B=2, L=24, C=16, H=W=64 fp32. align_corners=False, zero pad, x wrapped into [-1,1).
//
// R5 structure (resubmitted; never benched due to GPU timeout): channels-last imgT in
// d_ws (64B pixel records). One 64-thread block per (b,t,y): the wave handles one row x
// ALL 16 channels -> 16 independent dwordx4 gathers per k-step (MLP=16), coords computed
// once per row. bid&7 carries y%8 so each XCD's L2 holds a ~1MB y-band working set.

#define BB 2
#define LL 24
#define CC 16
#define HH 64
#define WW 64
#define HW (HH * WW)

// ---------- coordinate helper (exact wrap semantics, matches reference bitwise) ----------
__device__ __forceinline__ void bilin_coords(
    float gxv0, float gyv,
    int& i00, int& i10, int& i01, int& i11,
    float& w00, float& w10, float& w01, float& w11)
{
    // wrap x into [-1,1): remainder(gxv0+1, 2) - 1; exact fmod for |v|<4
    const float v = gxv0 + 1.0f;
    float r = v - 2.0f * truncf(v * 0.5f);
    r = (r < 0.0f) ? (r + 2.0f) : r;
    const float gxv = r - 1.0f;

    const float ix = (gxv + 1.0f) * 32.0f - 0.5f;
    const float iy = (gyv + 1.0f) * 32.0f - 0.5f;

    const float x0f = floorf(ix);
    const float y0f = floorf(iy);
    const float x1f = x0f + 1.0f;
    const float y1f = y0f + 1.0f;

    const float wx1 = ix - x0f, wx0 = 1.0f - wx1;
    const float wy1 = iy - y0f, wy0 = 1.0f - wy1;

    const bool vx0 = (x0f >= 0.0f) && (x0f <= 63.0f);
    const bool vx1 = (x1f >= 0.0f) && (x1f <= 63.0f);
    const bool vy0 = (y0f >= 0.0f) && (y0f <= 63.0f);
    const bool vy1 = (y1f >= 0.0f) && (y1f <= 63.0f);

    const int x0 = min(max((int)x0f, 0), WW - 1);
    const int x1 = min(max((int)x1f, 0), WW - 1);
    const int y0 = min(max((int)y0f, 0), HH - 1);
    const int y1 = min(max((int)y1f, 0), HH - 1);

    w00 = (vx0 && vy0) ? (wx0 * wy0) : 0.0f;
    w10 = (vx1 && vy0) ? (wx1 * wy0) : 0.0f;
    w01 = (vx0 && vy1) ? (wx0 * wy1) : 0.0f;
    w11 = (vx1 && vy1) ? (wx1 * wy1) : 0.0f;

    i00 = y0 * WW + x0;
    i10 = y0 * WW + x1;
    i01 = y1 * WW + x0;
    i11 = y1 * WW + x1;
}

// ---------- kernel 1: images [B,L,C,H,W] -> imgT [B,L,H,W,C] ----------
__global__ __launch_bounds__(64) void transpose_kernel(
    const float* __restrict__ img, float* __restrict__ imgT)
{
    const int bid = blockIdx.x;            // (b*L + l)*H + y, total B*L*H = 3072
    const int y = bid % HH;
    const int l = (bid / HH) % LL;
    const int b = bid / (HH * LL);
    const int x = threadIdx.x;

    const float* src = img + ((size_t)(b * LL + l) * CC) * HW + y * WW + x;
    float v[CC];
#pragma unroll
    for (int c = 0; c < CC; ++c) v[c] = src[(size_t)c * HW];

    float* dst = imgT + ((size_t)(b * LL + l) * HW + y * WW + x) * CC;
#pragma unroll
    for (int c = 0; c < CC; c += 4)
        *(float4*)(dst + c) = make_float4(v[c], v[c + 1], v[c + 2], v[c + 3]);
}

// ---------- kernel 2: main. 1 wave = 1 row x 16 channels, 16 gathers in flight ----------
__global__ __launch_bounds__(64) void gsps_main(
    const float* __restrict__ flows,   // [B,L,2,H,W]
    const float* __restrict__ imgT,    // [B,L,H,W,C] (64B pixel records)
    float* __restrict__ out)           // [B,L,C,H,W]
{
    // bid layout: y%8 in bid&7 so each XCD (round-robin on bid%8) owns y%8 == const
    // -> ~1MB gather working set per XCD-L2.
    const int bid = blockIdx.x;
    const int y_lo = bid & 7;
    const int r1 = bid >> 3;                 // [0, 384)
    const int t = (LL - 1) - (r1 % LL);      // big-t first within each XCD stripe
    const int r2 = r1 / LL;                  // [0, 16)
    const int y = ((r2 & 7) << 3) | y_lo;
    const int b = r2 >> 3;
    const int x = threadIdx.x;               // one wave = one row

    const float gx = -0.984375f + (float)x * 0.03125f;
    const float gy = -0.984375f + (float)y * 0.03125f;
    const int pix = y * WW + x;
    const float* fb = flows + (size_t)b * LL * 2 * HW + pix;

    // pass 1: cum[t] in ascending sequential order (bit-matches jnp.cumsum)
    float ctx = 0.0f, cty = 0.0f;
    for (int i = 0; i <= t; ++i) {
        ctx += fb[(size_t)(2 * i) * HW];
        cty += fb[(size_t)(2 * i + 1) * HW];
    }

    float acc[CC];
#pragma unroll
    for (int c = 0; c < CC; ++c) acc[c] = 0.0f;

    const char* pb = (const char*)imgT + (size_t)b * LL * HW * 64;  // 64B/pixel
    float cx = 0.0f, cy = 0.0f;
    float fkx = fb[0], fky = fb[HW];         // flow[0]

    for (int k = 0; k <= t; ++k) {
        cx += fkx; cy += fky;                // cum[k]
        // prefetch flow[k+1]: oldest vmcnt entry, latency hidden under this iter's consume
        if (k < t) {
            fkx = fb[(size_t)(2 * (k + 1)) * HW];
            fky = fb[(size_t)(2 * (k + 1) + 1) * HW];
        }

        int i00, i10, i01, i11;
        float w00, w10, w01, w11;
        bilin_coords(gx + (ctx - cx), gy + (cty - cy), i00, i10, i01, i11, w00, w10, w01, w11);

        const char* plane = pb + (size_t)k * (HW * 64);
        const float4* r00 = (const float4*)(plane + (size_t)i00 * 64);
        const float4* r10 = (const float4*)(plane + (size_t)i10 * 64);
        const float4* r01 = (const float4*)(plane + (size_t)i01 * 64);
        const float4* r11 = (const float4*)(plane + (size_t)i11 * 64);

        // issue all 16 dwordx4 gathers before any FMA (compiler drains vmcnt progressively)
        float4 v00[4], v10[4], v01[4], v11[4];
#pragma unroll
        for (int j = 0; j < 4; ++j) v00[j] = r00[j];
#pragma unroll
        for (int j = 0; j < 4; ++j) v10[j] = r10[j];
#pragma unroll
        for (int j = 0; j < 4; ++j) v01[j] = r01[j];
#pragma unroll
        for (int j = 0; j < 4; ++j) v11[j] = r11[j];

#pragma unroll
        for (int j = 0; j < 4; ++j) {
            acc[4 * j + 0] += v00[j].x * w00 + v10[j].x * w10 + v01[j].x * w01 + v11[j].x * w11;
            acc[4 * j + 1] += v00[j].y * w00 + v10[j].y * w10 + v01[j].y * w01 + v11[j].y * w11;
            acc[4 * j + 2] += v00[j].z * w00 + v10[j].z * w10 + v01[j].z * w01 + v11[j].z * w11;
            acc[4 * j + 3] += v00[j].w * w00 + v10[j].w * w10 + v01[j].w * w01 + v11[j].w * w11;
        }
    }

    float* o = out + ((size_t)(b * LL + t) * CC) * HW + pix;
#pragma unroll
    for (int c = 0; c < CC; ++c) o[(size_t)c * HW] = acc[c];
}

// ---------- fallback (ws too small): channels-first scalar gathers, 4 ch/wave ----------
__global__ __launch_bounds__(256) void gsps_direct(
    const float* __restrict__ flows,
    const float* __restrict__ images,  // [B,L,C,H,W]
    float* __restrict__ out)
{
    const int bid = blockIdx.x;
    const int t = (LL - 1) - (bid % LL);
    const int y = (bid / LL) % HH;
    const int b = bid / (LL * HH);
    const int x = threadIdx.x & 63;
    const int wave = threadIdx.x >> 6;
    const int cw = wave * 4;

    const float gx = -0.984375f + (float)x * 0.03125f;
    const float gy = -0.984375f + (float)y * 0.03125f;
    const int pix = y * WW + x;
    const float* fb = flows + (size_t)b * LL * 2 * HW + pix;

    float ctx = 0.0f, cty = 0.0f;
    for (int i = 0; i <= t; ++i) {
        ctx += fb[(size_t)(i * 2) * HW];
        cty += fb[(size_t)(i * 2 + 1) * HW];
    }

    float acc[4] = {0.0f, 0.0f, 0.0f, 0.0f};
    float cx = 0.0f, cy = 0.0f;
    float fxk = fb[0];
    float fyk = fb[HW];

    for (int k = 0; k <= t; ++k) {
        cx += fxk; cy += fyk;
        if (k < t) {
            fxk = fb[(size_t)((k + 1) * 2) * HW];
            fyk = fb[(size_t)((k + 1) * 2 + 1) * HW];
        }

        int i00, i10, i01, i11;
        float w00, w10, w01, w11;
        bilin_coords(gx + (ctx - cx), gy + (cty - cy), i00, i10, i01, i11, w00, w10, w01, w11);

        const float* img = images + (((size_t)(b * LL + k) * CC) + cw) * HW;
#pragma unroll
        for (int c = 0; c < 4; ++c) {
            const float* pc = img + (size_t)c * HW;
            acc[c] += pc[i00] * w00 + pc[i10] * w10 + pc[i01] * w01 + pc[i11] * w11;
        }
    }

    float* o = out + ((size_t)(b * LL + t) * CC + cw) * HW + pix;
#pragma unroll
    for (int c = 0; c < 4; ++c) o[(size_t)c * HW] = acc[c];
}

extern "C" void kernel_launch(void* const* d_in, const int* in_sizes, int n_in,
                              void* d_out, int out_size, void* d_ws, size_t ws_size,
                              hipStream_t stream) {
    const float* flows  = (const float*)d_in[0];   // [B,L,2,H,W]
    const float* images = (const float*)d_in[1];   // [B,L,C,H,W]
    float* out = (float*)d_out;                    // [B,L,C,H,W]

    const size_t needT = (size_t)BB * LL * CC * HW * sizeof(float);  // 12.6 MB
    const int nblk = BB * LL * HH;                                   // 3072

    if (ws_size >= needT) {
        float* imgT = (float*)d_ws;
        transpose_kernel<<<nblk, 64, 0, stream>>>(images, imgT);
        gsps_main<<<nblk, 64, 0, stream>>>(flows, imgT, out);
    } else {
        gsps_direct<<<nblk, 256, 0, stream>>>(flows, images, out);
    }
}